// Round 6
// baseline (356.653 us; speedup 1.0000x reference)
//
#include <hip/hip_runtime.h>
#include <hip/hip_bf16.h>

// Self-guided-filter loss, fused per 32x32 tile. v6: concurrency-first.
//  - h1 computed in 2 vertical halves (31 rows) -> LDS 25.9 KB -> 6 blocks/CU.
//  - h2 reuses the A/B region (P6: read-all-to-regs, barrier, write-in-place).
//  - P7 runs on wave 3 only, overlapped with the NEXT image's P2 (waves 0-2).
//  - bank-uniform task maps; all LDS buffer offsets 32-dword aligned.
// (8,3,512,512) fp32, RADIUS=5 (k=11), EPS=1e-6.

#define W 512
#define TB 32
#define H1STR 44
#define ABSTR 44
#define H2STR 36

#define O_H1X 0
#define O_H1Y 1376
#define O_A   2752
#define O_B   4608
#define O_H2A 2752
#define O_H2B 4288
#define S_FLOATS 6464   // 25,856 B -> 6 blocks/CU

#define NBLK_X 16
#define NBLK_Y 16
#define NPLANES 24
#define NPARTIALS (NBLK_X*NBLK_Y*NPLANES)
#define TOTAL_ELEMS 6291456.0
#define INV121 (1.0f/121.0f)

__device__ __forceinline__ float4 ld4(const float* p) { return *(const float4*)p; }

// ---- P2 half: global -> h1 horizontal 11-sums of x, x^2. 186 tasks (waves 0-2):
// 31 rows x 6 col-groups; h1 buf row r <-> img row IMGROW0+r.
#define P2_HALF(XP, IMGROW0)                                                  \
    if (tid < 186) {                                                          \
        int r = tid / 6, cg = tid - r * 6;                                    \
        int j0 = cg * 8;                    /* cg==5 -> j0=40, writes 2 */    \
        float* hx = &S[O_H1X + r * H1STR + j0];                               \
        float* hy = &S[O_H1Y + r * H1STR + j0];                               \
        int gy = (IMGROW0) + r;                                               \
        float w[20];                                                          \
        if ((unsigned)gy < (unsigned)W) {                                     \
            const float* Xr = (XP) + (size_t)gy * W;                          \
            int gx0 = tx0 - 12 + j0;                                          \
            if (gx0 >= 0 && gx0 + 20 <= W) {                                  \
                const float4* p = (const float4*)(Xr + gx0);                  \
                float4 v0=p[0],v1=p[1],v2=p[2],v3=p[3],v4=p[4];               \
                w[0]=v0.x;  w[1]=v0.y;  w[2]=v0.z;  w[3]=v0.w;                \
                w[4]=v1.x;  w[5]=v1.y;  w[6]=v1.z;  w[7]=v1.w;                \
                w[8]=v2.x;  w[9]=v2.y;  w[10]=v2.z; w[11]=v2.w;               \
                w[12]=v3.x; w[13]=v3.y; w[14]=v3.z; w[15]=v3.w;               \
                w[16]=v4.x; w[17]=v4.y; w[18]=v4.z; w[19]=v4.w;               \
            } else {                                                          \
                _Pragma("unroll")                                             \
                for (int k = 0; k < 20; ++k) {                                \
                    int gx = gx0 + k;                                         \
                    w[k] = ((unsigned)gx < (unsigned)W) ? Xr[gx] : 0.f;       \
                }                                                             \
            }                                                                 \
        } else {                                                              \
            _Pragma("unroll")                                                 \
            for (int k = 0; k < 20; ++k) w[k] = 0.f;                          \
        }                                                                     \
        float o[8], u[8];                                                     \
        float s = w[2]+w[3]+w[4]+w[5]+w[6]+w[7]+w[8]+w[9]+w[10]+w[11]+w[12];  \
        o[0] = s;                                                             \
        _Pragma("unroll")                                                     \
        for (int k = 1; k < 8; ++k) { s += w[12+k] - w[1+k]; o[k] = s; }      \
        float sq[20];                                                         \
        _Pragma("unroll")                                                     \
        for (int k = 2; k < 20; ++k) sq[k] = w[k]*w[k];                       \
        float s2 = sq[2]+sq[3]+sq[4]+sq[5]+sq[6]+sq[7]+sq[8]+sq[9]+sq[10]     \
                 +sq[11]+sq[12];                                              \
        u[0] = s2;                                                            \
        _Pragma("unroll")                                                     \
        for (int k = 1; k < 8; ++k) { s2 += sq[12+k] - sq[1+k]; u[k] = s2; }  \
        if (cg < 5) {                                                         \
            *(float4*)hx     = make_float4(o[0],o[1],o[2],o[3]);              \
            *(float4*)(hx+4) = make_float4(o[4],o[5],o[6],o[7]);              \
            *(float4*)hy     = make_float4(u[0],u[1],u[2],u[3]);              \
            *(float4*)(hy+4) = make_float4(u[4],u[5],u[6],u[7]);              \
        } else {                                                              \
            *(float2*)hx = make_float2(o[0], o[1]);                           \
            *(float2*)hy = make_float2(u[0], u[1]);                           \
        }                                                                     \
    }

// ---- P4 half: vertical 11-sums over h1 -> a,b. 22 tasks, interleaved lane map
// (cg=tid>>1, chunk=tid&1 -> bank-uniform). A rows Q0..Q0+20.
#define P4_HALF(Q0)                                                           \
    if (tid < 22) {                                                           \
        int cg = tid >> 1, chunk = tid & 1;                                   \
        int c4 = cg * 4;                                                      \
        int r0b = chunk * 11;                                                 \
        int qa = (Q0) + chunk * 11;                                           \
        int L = chunk ? 10 : 11;                                              \
        float mv0 = ((unsigned)(tx0-5+c4+0) < (unsigned)W) ? INV121 : 0.f;    \
        float mv1 = ((unsigned)(tx0-5+c4+1) < (unsigned)W) ? INV121 : 0.f;    \
        float mv2 = ((unsigned)(tx0-5+c4+2) < (unsigned)W) ? INV121 : 0.f;    \
        float mv3 = ((unsigned)(tx0-5+c4+3) < (unsigned)W) ? INV121 : 0.f;    \
        const float* hx = &S[O_H1X + c4];                                     \
        const float* hy = &S[O_H1Y + c4];                                     \
        float sx0=0,sx1=0,sx2=0,sx3=0, sy0=0,sy1=0,sy2=0,sy3=0;               \
        _Pragma("unroll")                                                     \
        for (int d = 0; d < 10; ++d) {                                        \
            float4 xn = ld4(hx + (r0b+d)*H1STR);                              \
            float4 yn = ld4(hy + (r0b+d)*H1STR);                              \
            sx0+=xn.x; sx1+=xn.y; sx2+=xn.z; sx3+=xn.w;                       \
            sy0+=yn.x; sy1+=yn.y; sy2+=yn.z; sy3+=yn.w;                       \
        }                                                                     \
        for (int j = 0; j < L; ++j) {                                         \
            {                                                                 \
                float4 xn = ld4(hx + (r0b+10+j)*H1STR);                       \
                float4 yn = ld4(hy + (r0b+10+j)*H1STR);                       \
                sx0+=xn.x; sx1+=xn.y; sx2+=xn.z; sx3+=xn.w;                   \
                sy0+=yn.x; sy1+=yn.y; sy2+=yn.z; sy3+=yn.w;                   \
            }                                                                 \
            int q = qa + j;                                                   \
            int gy = ty0 - 5 + q;                                             \
            float4 av, bv;                                                    \
            if ((unsigned)gy < (unsigned)W) {                                 \
                float m0=sx0*mv0, c0=sy0*mv0, m1=sx1*mv1, c1=sy1*mv1;         \
                float m2=sx2*mv2, c2=sy2*mv2, m3=sx3*mv3, c3=sy3*mv3;         \
                float va0=fmaf(-m0,m0,c0), va1=fmaf(-m1,m1,c1);               \
                float va2=fmaf(-m2,m2,c2), va3=fmaf(-m3,m3,c3);               \
                float a0=va0*__builtin_amdgcn_rcpf(va0+1e-6f);                \
                float a1=va1*__builtin_amdgcn_rcpf(va1+1e-6f);                \
                float a2=va2*__builtin_amdgcn_rcpf(va2+1e-6f);                \
                float a3=va3*__builtin_amdgcn_rcpf(va3+1e-6f);                \
                av = make_float4(a0,a1,a2,a3);                                \
                bv = make_float4(fmaf(-a0,m0,m0), fmaf(-a1,m1,m1),            \
                                 fmaf(-a2,m2,m2), fmaf(-a3,m3,m3));           \
            } else { av = make_float4(0.f,0.f,0.f,0.f); bv = av; }            \
            *(float4*)&S[O_A + q*ABSTR + c4] = av;                            \
            *(float4*)&S[O_B + q*ABSTR + c4] = bv;                            \
            {                                                                 \
                float4 xo = ld4(hx + (r0b+j)*H1STR);                          \
                float4 yo = ld4(hy + (r0b+j)*H1STR);                          \
                sx0-=xo.x; sx1-=xo.y; sx2-=xo.z; sx3-=xo.w;                   \
                sy0-=yo.x; sy1-=yo.y; sy2-=yo.z; sy3-=yo.w;                   \
            }                                                                 \
        }                                                                     \
    }

// ---- P7 step: one output row; flit in named regs (wave 3 only).
#define P7_STEP(XP, IMG, J, G0, G1, G2, G3)                                   \
    {                                                                         \
        int q = r0 + J;                                                       \
        float4 a = ld4(ha + (q + 10) * H2STR);                                \
        float4 b = ld4(hb + (q + 10) * H2STR);                                \
        sa0+=a.x; sa1+=a.y; sa2+=a.z; sa3+=a.w;                               \
        sb0+=b.x; sb1+=b.y; sb2+=b.z; sb3+=b.w;                               \
        float4 xv = ld4((XP) + (size_t)(ty0 + q) * W + (tx0 + c4));           \
        float t0 = fmaf(sa0, xv.x, sb0), g0 = fmaf(-t0, INV121, xv.x);        \
        float t1 = fmaf(sa1, xv.y, sb1), g1 = fmaf(-t1, INV121, xv.y);        \
        float t2 = fmaf(sa2, xv.z, sb2), g2 = fmaf(-t2, INV121, xv.z);        \
        float t3 = fmaf(sa3, xv.w, sb3), g3 = fmaf(-t3, INV121, xv.w);        \
        if ((IMG) == 0) {                                                     \
            G0 = fabsf(g0); G1 = fabsf(g1); G2 = fabsf(g2); G3 = fabsf(g3);   \
        } else if ((IMG) == 1) {                                              \
            G0 = fmaxf(G0, fabsf(g0)); G1 = fmaxf(G1, fabsf(g1));             \
            G2 = fmaxf(G2, fabsf(g2)); G3 = fmaxf(G3, fabsf(g3));             \
        } else {                                                              \
            acc += fabsf(g0 - G0) + fabsf(g1 - G1)                            \
                 + fabsf(g2 - G2) + fabsf(g3 - G3);                           \
        }                                                                     \
        float4 ao_ = ld4(ha + q * H2STR);                                     \
        float4 bo_ = ld4(hb + q * H2STR);                                     \
        sa0-=ao_.x; sa1-=ao_.y; sa2-=ao_.z; sa3-=ao_.w;                       \
        sb0-=bo_.x; sb1-=bo_.y; sb2-=bo_.z; sb3-=bo_.w;                       \
    }

#define P7_PHASE(XP, IMG)                                                     \
    {                                                                         \
        int t7 = tid - 192;                                                   \
        int chunk = t7 >> 3, cg = t7 & 7;                                     \
        int r0 = chunk * 4, c4 = cg * 4;                                      \
        const float* ha = &S[O_H2A + c4];                                     \
        const float* hb = &S[O_H2B + c4];                                     \
        float sa0=0,sa1=0,sa2=0,sa3=0, sb0=0,sb1=0,sb2=0,sb3=0;               \
        _Pragma("unroll")                                                     \
        for (int d = 0; d < 10; ++d) {                                        \
            float4 a = ld4(ha + (r0+d)*H2STR);                                \
            float4 b = ld4(hb + (r0+d)*H2STR);                                \
            sa0+=a.x; sa1+=a.y; sa2+=a.z; sa3+=a.w;                           \
            sb0+=b.x; sb1+=b.y; sb2+=b.z; sb3+=b.w;                           \
        }                                                                     \
        P7_STEP(XP, IMG, 0, F00,F01,F02,F03)                                  \
        P7_STEP(XP, IMG, 1, F10,F11,F12,F13)                                  \
        P7_STEP(XP, IMG, 2, F20,F21,F22,F23)                                  \
        P7_STEP(XP, IMG, 3, F30,F31,F32,F33)                                  \
    }

__global__ __launch_bounds__(256, 6) void sgf_loss_kernel(
    const float* __restrict__ gen, const float* __restrict__ ir,
    const float* __restrict__ vi, float* __restrict__ partials)
{
    __shared__ __align__(16) float S[S_FLOATS];
    const int tid = threadIdx.x;
    const int tx0 = blockIdx.x * TB;
    const int ty0 = blockIdx.y * TB;
    const size_t pbase = (size_t)blockIdx.z * (W * W);

    float acc = 0.0f;
    float F00=0,F01=0,F02=0,F03=0, F10=0,F11=0,F12=0,F13=0;
    float F20=0,F21=0,F22=0,F23=0, F30=0,F31=0,F32=0,F33=0;

    const float* prevX = nullptr;

    #pragma unroll 1
    for (int img = 0; img < 3; ++img) {
        const float* __restrict__ X =
            (img == 0 ? ir : (img == 1 ? vi : gen)) + pbase;

        // wave 3: finish previous image (reads h2 in A/B region) while
        // waves 0-2 start this image's P2a (writes h1 only). P4a (writes A/B)
        // comes after the barrier wave 3 must reach.
        if (img > 0 && tid >= 192) { P7_PHASE(prevX, (img - 1)) }

        P2_HALF(X, ty0 - 10)        // h1 rows = img rows ty0-10 .. ty0+20
        __syncthreads();
        P4_HALF(0)                  // A,B rows 0..20
        __syncthreads();
        P2_HALF(X, ty0 + 11)        // h1 rows = img rows ty0+11 .. ty0+41
        __syncthreads();
        P4_HALF(21)                 // A,B rows 21..41
        __syncthreads();

        // ---- P6: horizontal 11-sums of a,b -> h2 (in place over A/B region).
        // 168 tasks: read+sum to regs, barrier, write.
        float oa[8], ob[8];
        int p6r = tid >> 2, p6j0 = (tid & 3) * 8;
        if (tid < 168) {
            const float* Ap = &S[O_A + p6r * ABSTR + p6j0];
            const float* Bp = &S[O_B + p6r * ABSTR + p6j0];
            float wa[20], wb[20];
            #pragma unroll
            for (int k = 0; k < 5; ++k) {
                float4 va = ld4(Ap + 4*k);
                wa[4*k]=va.x; wa[4*k+1]=va.y; wa[4*k+2]=va.z; wa[4*k+3]=va.w;
                float4 vb = ld4(Bp + 4*k);
                wb[4*k]=vb.x; wb[4*k+1]=vb.y; wb[4*k+2]=vb.z; wb[4*k+3]=vb.w;
            }
            float s = wa[0]+wa[1]+wa[2]+wa[3]+wa[4]+wa[5]+wa[6]+wa[7]+wa[8]
                    +wa[9]+wa[10];
            oa[0] = s;
            #pragma unroll
            for (int k = 1; k < 8; ++k) { s += wa[10+k] - wa[k-1]; oa[k] = s; }
            float s2 = wb[0]+wb[1]+wb[2]+wb[3]+wb[4]+wb[5]+wb[6]+wb[7]+wb[8]
                     +wb[9]+wb[10];
            ob[0] = s2;
            #pragma unroll
            for (int k = 1; k < 8; ++k) { s2 += wb[10+k] - wb[k-1]; ob[k] = s2; }
        }
        __syncthreads();
        if (tid < 168) {
            float* da = &S[O_H2A + p6r * H2STR + p6j0];
            float* db = &S[O_H2B + p6r * H2STR + p6j0];
            *(float4*)da     = make_float4(oa[0],oa[1],oa[2],oa[3]);
            *(float4*)(da+4) = make_float4(oa[4],oa[5],oa[6],oa[7]);
            *(float4*)db     = make_float4(ob[0],ob[1],ob[2],ob[3]);
            *(float4*)(db+4) = make_float4(ob[4],ob[5],ob[6],ob[7]);
        }
        __syncthreads();

        prevX = X;
    }

    // final P7 (gen) + wave-3 reduction
    if (tid >= 192) {
        P7_PHASE(prevX, 2)
        #pragma unroll
        for (int off = 32; off > 0; off >>= 1) acc += __shfl_down(acc, off);
        if (tid == 192)
            partials[((blockIdx.z * NBLK_Y) + blockIdx.y) * NBLK_X + blockIdx.x] = acc;
    }
}

__global__ __launch_bounds__(256) void sgf_final_reduce(
    const float* __restrict__ partials, float* __restrict__ out)
{
    __shared__ double sd[256];
    int tid = threadIdx.x;
    double s = 0.0;
    for (int i = tid; i < NPARTIALS; i += 256) s += (double)partials[i];
    sd[tid] = s;
    __syncthreads();
    for (int off = 128; off > 0; off >>= 1) {
        if (tid < off) sd[tid] += sd[tid + off];
        __syncthreads();
    }
    if (tid == 0) out[0] = (float)(sd[0] * (1.0 / TOTAL_ELEMS));
}

extern "C" void kernel_launch(void* const* d_in, const int* in_sizes, int n_in,
                              void* d_out, int out_size, void* d_ws, size_t ws_size,
                              hipStream_t stream) {
    const float* gen = (const float*)d_in[0];
    const float* ir  = (const float*)d_in[1];
    const float* vi  = (const float*)d_in[2];
    float* partials = (float*)d_ws;   // 6144 floats = 24 KB

    dim3 grid(NBLK_X, NBLK_Y, NPLANES);
    sgf_loss_kernel<<<grid, dim3(256), 0, stream>>>(gen, ir, vi, partials);
    sgf_final_reduce<<<1, dim3(256), 0, stream>>>(partials, (float*)d_out);
}

// Round 7
// 284.089 us; speedup vs baseline: 1.2554x; 1.2554x over previous
//
#include <hip/hip_runtime.h>
#include <hip/hip_bf16.h>

// Self-guided-filter loss, fused per 32x32 tile. v7: latency-bound fixes.
//  - LDS 32,352 B -> 5 blocks/CU (stride-43 h1/A/B, h2 aliases h1).
//  - P7 direct 11-tap, 256 tasks (all waves), flit = 4 named regs/thread.
//  - P4 chunk=3 -> 154 tasks, one round, short chains.
//  - NO forced-low register cap (v6 spill post-mortem).
// (8,3,512,512) fp32, RADIUS=5 (k=11), EPS=1e-6.

#define W 512
#define TB 32
#define H1STR 43   // h1: 52 rows, cols 0..41 valid
#define ABSTR 43   // A,B: 42 rows, cols 0..41 valid
#define H2STR 36   // h2: 42 rows, cols 0..31

#define O_H1X 0        // 52*43 = 2236
#define O_H1Y 2236     // 2236
#define O_A   4472     // 42*43 = 1806
#define O_B   6278     // 1806
#define O_H2A 0        // aliases h1x (dead after P4); 42*36 = 1512
#define O_H2B 2236     // aliases h1y
#define S_FLOATS 8088  // 32,352 B -> 5 blocks/CU

#define NBLK_X 16
#define NBLK_Y 16
#define NPLANES 24
#define NPARTIALS (NBLK_X*NBLK_Y*NPLANES)
#define TOTAL_ELEMS 6291456.0
#define INV121 (1.0f/121.0f)

__device__ __forceinline__ float4 ld4(const float* p) { return *(const float4*)p; }

__global__ __launch_bounds__(256, 5) void sgf_loss_kernel(
    const float* __restrict__ gen, const float* __restrict__ ir,
    const float* __restrict__ vi, float* __restrict__ partials)
{
    __shared__ __align__(16) float S[S_FLOATS];
    const int tid = threadIdx.x;
    const int tx0 = blockIdx.x * TB;
    const int ty0 = blockIdx.y * TB;
    const size_t pbase = (size_t)blockIdx.z * (W * W);

    float acc = 0.0f;
    float F0 = 0.f, F1 = 0.f, F2 = 0.f, F3 = 0.f;   // flit state (per-thread pixel4)

    #pragma unroll 1
    for (int img = 0; img < 3; ++img) {
        const float* __restrict__ X =
            (img == 0 ? ir : (img == 1 ? vi : gen)) + pbase;

        __syncthreads();   // h2 (aliased h1) read in prev P7 finishes before P2 writes

        // ---- P2: global -> h1 horizontal 11-sums of x, x^2.
        // 312 tasks: 52 rows x 6 col-groups (cg<5: 8 outputs, cg==5: 2 outputs).
        for (int t = tid; t < 312; t += 256) {
            int r = t / 6, cg = t - r * 6;
            int j0 = cg * 8;
            float* hx = &S[O_H1X + r * H1STR + j0];
            float* hy = &S[O_H1Y + r * H1STR + j0];
            int gy = ty0 - 10 + r;
            float w[20];
            if ((unsigned)gy < (unsigned)W) {
                const float* Xr = X + (size_t)gy * W;
                int gx0 = tx0 - 12 + j0;           // 16B-aligned
                if (gx0 >= 0 && gx0 + 20 <= W) {
                    const float4* p = (const float4*)(Xr + gx0);
                    float4 v0=p[0],v1=p[1],v2=p[2],v3=p[3],v4=p[4];
                    w[0]=v0.x;  w[1]=v0.y;  w[2]=v0.z;  w[3]=v0.w;
                    w[4]=v1.x;  w[5]=v1.y;  w[6]=v1.z;  w[7]=v1.w;
                    w[8]=v2.x;  w[9]=v2.y;  w[10]=v2.z; w[11]=v2.w;
                    w[12]=v3.x; w[13]=v3.y; w[14]=v3.z; w[15]=v3.w;
                    w[16]=v4.x; w[17]=v4.y; w[18]=v4.z; w[19]=v4.w;
                } else {
                    #pragma unroll
                    for (int k = 0; k < 20; ++k) {
                        int gx = gx0 + k;
                        w[k] = ((unsigned)gx < (unsigned)W) ? Xr[gx] : 0.f;
                    }
                }
            } else {
                #pragma unroll
                for (int k = 0; k < 20; ++k) w[k] = 0.f;
            }
            float o[8], u[8];
            float s = w[2]+w[3]+w[4]+w[5]+w[6]+w[7]+w[8]+w[9]+w[10]+w[11]+w[12];
            o[0] = s;
            #pragma unroll
            for (int k = 1; k < 8; ++k) { s += w[12+k] - w[1+k]; o[k] = s; }
            float sq[20];
            #pragma unroll
            for (int k = 2; k < 20; ++k) sq[k] = w[k]*w[k];
            float s2 = sq[2]+sq[3]+sq[4]+sq[5]+sq[6]+sq[7]+sq[8]+sq[9]+sq[10]
                     +sq[11]+sq[12];
            u[0] = s2;
            #pragma unroll
            for (int k = 1; k < 8; ++k) { s2 += sq[12+k] - sq[1+k]; u[k] = s2; }
            if (cg < 5) {
                *(float4*)hx     = make_float4(o[0],o[1],o[2],o[3]);
                *(float4*)(hx+4) = make_float4(o[4],o[5],o[6],o[7]);
                *(float4*)hy     = make_float4(u[0],u[1],u[2],u[3]);
                *(float4*)(hy+4) = make_float4(u[4],u[5],u[6],u[7]);
            } else {
                *(float2*)hx = make_float2(o[0], o[1]);   // cols 40,41
                *(float2*)hy = make_float2(u[0], u[1]);
            }
        }
        __syncthreads();

        // ---- P4: vertical 11-sums over h1 -> a,b. 154 tasks, ONE round:
        // cg 0..10 (cols 4cg..4cg+3), chunk 0..13 (A rows 3*chunk..3*chunk+2).
        if (tid < 154) {
            int chunk = tid / 11, cg = tid - chunk * 11;
            int q0 = chunk * 3, c4 = cg * 4;
            float mv0 = ((unsigned)(tx0-5+c4+0) < (unsigned)W) ? INV121 : 0.f;
            float mv1 = ((unsigned)(tx0-5+c4+1) < (unsigned)W) ? INV121 : 0.f;
            float mv2 = ((unsigned)(tx0-5+c4+2) < (unsigned)W) ? INV121 : 0.f;
            float mv3 = ((unsigned)(tx0-5+c4+3) < (unsigned)W) ? INV121 : 0.f;
            const float* hx = &S[O_H1X + c4];
            const float* hy = &S[O_H1Y + c4];
            float sx0=0,sx1=0,sx2=0,sx3=0, sy0=0,sy1=0,sy2=0,sy3=0;
            #pragma unroll
            for (int d = 0; d < 10; ++d) {
                float4 xn = ld4(hx + (q0+d)*H1STR);
                float4 yn = ld4(hy + (q0+d)*H1STR);
                sx0+=xn.x; sx1+=xn.y; sx2+=xn.z; sx3+=xn.w;
                sy0+=yn.x; sy1+=yn.y; sy2+=yn.z; sy3+=yn.w;
            }
#define P4_ROW(J)                                                             \
            {                                                                 \
                int q = q0 + (J);                                             \
                float4 xn = ld4(hx + (q+10)*H1STR);                           \
                float4 yn = ld4(hy + (q+10)*H1STR);                           \
                sx0+=xn.x; sx1+=xn.y; sx2+=xn.z; sx3+=xn.w;                   \
                sy0+=yn.x; sy1+=yn.y; sy2+=yn.z; sy3+=yn.w;                   \
                int gy = ty0 - 5 + q;                                         \
                float4 av, bv;                                                \
                if ((unsigned)gy < (unsigned)W) {                             \
                    float m0=sx0*mv0, c0=sy0*mv0, m1=sx1*mv1, c1=sy1*mv1;     \
                    float m2=sx2*mv2, c2=sy2*mv2, m3=sx3*mv3, c3=sy3*mv3;     \
                    float va0=fmaf(-m0,m0,c0), va1=fmaf(-m1,m1,c1);           \
                    float va2=fmaf(-m2,m2,c2), va3=fmaf(-m3,m3,c3);           \
                    float a0=va0*__builtin_amdgcn_rcpf(va0+1e-6f);            \
                    float a1=va1*__builtin_amdgcn_rcpf(va1+1e-6f);            \
                    float a2=va2*__builtin_amdgcn_rcpf(va2+1e-6f);            \
                    float a3=va3*__builtin_amdgcn_rcpf(va3+1e-6f);            \
                    av = make_float4(a0,a1,a2,a3);                            \
                    bv = make_float4(fmaf(-a0,m0,m0), fmaf(-a1,m1,m1),        \
                                     fmaf(-a2,m2,m2), fmaf(-a3,m3,m3));       \
                } else { av = make_float4(0.f,0.f,0.f,0.f); bv = av; }        \
                if (cg < 10) {                                                \
                    *(float4*)&S[O_A + q*ABSTR + c4] = av;                    \
                    *(float4*)&S[O_B + q*ABSTR + c4] = bv;                    \
                } else {                                                      \
                    *(float2*)&S[O_A + q*ABSTR + c4] = make_float2(av.x,av.y);\
                    *(float2*)&S[O_B + q*ABSTR + c4] = make_float2(bv.x,bv.y);\
                }                                                             \
                float4 xo = ld4(hx + q*H1STR);                                \
                float4 yo = ld4(hy + q*H1STR);                                \
                sx0-=xo.x; sx1-=xo.y; sx2-=xo.z; sx3-=xo.w;                   \
                sy0-=yo.x; sy1-=yo.y; sy2-=yo.z; sy3-=yo.w;                   \
            }
            P4_ROW(0) P4_ROW(1) P4_ROW(2)
#undef P4_ROW
        }
        __syncthreads();

        // ---- P6: horizontal 11-sums of a,b -> h2a,h2b (h1 region, dead).
        // 168 tasks (r 0..41, cg 0..3 -> 8 output cols each).
        if (tid < 168) {
            int r = tid >> 2, j0 = (tid & 3) * 8;
            const float* Ap = &S[O_A + r * ABSTR + j0];
            const float* Bp = &S[O_B + r * ABSTR + j0];
            float wa[20], wb[20];
            #pragma unroll
            for (int k = 0; k < 5; ++k) {
                float4 va = ld4(Ap + 4*k);
                wa[4*k]=va.x; wa[4*k+1]=va.y; wa[4*k+2]=va.z; wa[4*k+3]=va.w;
                float4 vb = ld4(Bp + 4*k);
                wb[4*k]=vb.x; wb[4*k+1]=vb.y; wb[4*k+2]=vb.z; wb[4*k+3]=vb.w;
            }
            float oa[8], ob[8];
            float s = wa[0]+wa[1]+wa[2]+wa[3]+wa[4]+wa[5]+wa[6]+wa[7]+wa[8]
                    +wa[9]+wa[10];
            oa[0] = s;
            #pragma unroll
            for (int k = 1; k < 8; ++k) { s += wa[10+k] - wa[k-1]; oa[k] = s; }
            float s2 = wb[0]+wb[1]+wb[2]+wb[3]+wb[4]+wb[5]+wb[6]+wb[7]+wb[8]
                     +wb[9]+wb[10];
            ob[0] = s2;
            #pragma unroll
            for (int k = 1; k < 8; ++k) { s2 += wb[10+k] - wb[k-1]; ob[k] = s2; }
            float* da = &S[O_H2A + r * H2STR + j0];
            float* db = &S[O_H2B + r * H2STR + j0];
            *(float4*)da     = make_float4(oa[0],oa[1],oa[2],oa[3]);
            *(float4*)(da+4) = make_float4(oa[4],oa[5],oa[6],oa[7]);
            *(float4*)db     = make_float4(ob[0],ob[1],ob[2],ob[3]);
            *(float4*)(db+4) = make_float4(ob[4],ob[5],ob[6],ob[7]);
        }
        __syncthreads();

        // ---- P7: DIRECT 11-tap vertical over h2 -> f; 256 tasks (all waves).
        // r = tid>>3 (out row 0..31), cg = tid&7 (cols 4cg..4cg+3).
        {
            int r = tid >> 3, c4 = (tid & 7) * 4;
            const float* ha = &S[O_H2A + c4];
            const float* hb = &S[O_H2B + c4];
            float sa0=0,sa1=0,sa2=0,sa3=0, sb0=0,sb1=0,sb2=0,sb3=0;
            #pragma unroll
            for (int d = 0; d < 11; ++d) {
                float4 a = ld4(ha + (r+d)*H2STR);
                float4 b = ld4(hb + (r+d)*H2STR);
                sa0+=a.x; sa1+=a.y; sa2+=a.z; sa3+=a.w;
                sb0+=b.x; sb1+=b.y; sb2+=b.z; sb3+=b.w;
            }
            float4 xv = ld4(X + (size_t)(ty0 + r) * W + (tx0 + c4));
            float t0 = fmaf(sa0, xv.x, sb0), g0 = fmaf(-t0, INV121, xv.x);
            float t1 = fmaf(sa1, xv.y, sb1), g1 = fmaf(-t1, INV121, xv.y);
            float t2 = fmaf(sa2, xv.z, sb2), g2 = fmaf(-t2, INV121, xv.z);
            float t3 = fmaf(sa3, xv.w, sb3), g3 = fmaf(-t3, INV121, xv.w);
            if (img == 0) {
                F0 = fabsf(g0); F1 = fabsf(g1); F2 = fabsf(g2); F3 = fabsf(g3);
            } else if (img == 1) {
                F0 = fmaxf(F0, fabsf(g0)); F1 = fmaxf(F1, fabsf(g1));
                F2 = fmaxf(F2, fabsf(g2)); F3 = fmaxf(F3, fabsf(g3));
            } else {
                acc += fabsf(g0 - F0) + fabsf(g1 - F1)
                     + fabsf(g2 - F2) + fabsf(g3 - F3);
            }
        }
    } // img loop

    // block reduction: wave shuffle + cross-wave via LDS
    #pragma unroll
    for (int off = 32; off > 0; off >>= 1) acc += __shfl_down(acc, off);
    __syncthreads();                // all P7 LDS reads done before S reuse
    if ((tid & 63) == 0) S[tid >> 6] = acc;
    __syncthreads();
    if (tid == 0)
        partials[((blockIdx.z * NBLK_Y) + blockIdx.y) * NBLK_X + blockIdx.x] =
            S[0] + S[1] + S[2] + S[3];
}

__global__ __launch_bounds__(256) void sgf_final_reduce(
    const float* __restrict__ partials, float* __restrict__ out)
{
    __shared__ double sd[256];
    int tid = threadIdx.x;
    double s = 0.0;
    for (int i = tid; i < NPARTIALS; i += 256) s += (double)partials[i];
    sd[tid] = s;
    __syncthreads();
    for (int off = 128; off > 0; off >>= 1) {
        if (tid < off) sd[tid] += sd[tid + off];
        __syncthreads();
    }
    if (tid == 0) out[0] = (float)(sd[0] * (1.0 / TOTAL_ELEMS));
}

extern "C" void kernel_launch(void* const* d_in, const int* in_sizes, int n_in,
                              void* d_out, int out_size, void* d_ws, size_t ws_size,
                              hipStream_t stream) {
    const float* gen = (const float*)d_in[0];
    const float* ir  = (const float*)d_in[1];
    const float* vi  = (const float*)d_in[2];
    float* partials = (float*)d_ws;   // 6144 floats = 24 KB

    dim3 grid(NBLK_X, NBLK_Y, NPLANES);
    sgf_loss_kernel<<<grid, dim3(256), 0, stream>>>(gen, ir, vi, partials);
    sgf_final_reduce<<<1, dim3(256), 0, stream>>>(partials, (float*)d_out);
}

// Round 8
// 162.384 us; speedup vs baseline: 2.1963x; 1.7495x over previous
//
#include <hip/hip_runtime.h>
#include <hip/hip_bf16.h>

// Self-guided-filter loss, fused per 32x32 tile. v8: vertical-then-horizontal
// in BOTH box stages to minimize LDS bytes; all LDS float4 strides %4==0.
//  - P2': vertical 11-sums of x,x^2 from GLOBAL -> V1 (no LDS reads).
//  - P4': horizontal 11-sums over V1 (contiguous windows, 8 b128/task) + a,b.
//  - P6': vertical 11-sums A/B -> V2 (sliding, 88 tasks).
//  - P7': horizontal 11-sums over V2 + finalize; flit in 4 named regs.
// LDS 32,256 B -> 5 blocks/CU. (8,3,512,512) fp32, RADIUS=5, EPS=1e-6.

#define W 512
#define TB 32
#define V1STR 52   // V1: 42 rows x 52 cols (img cols tx0-10..tx0+41)
#define ABSTR 44   // A,B: 42 rows x 42 cols valid (0..41), quad 10 has junk 42,43
#define V2STR 44   // V2: 32 rows x 42 cols valid

#define O_V1X 0       // 2184
#define O_V1Y 2184    // 2184
#define O_A   4368    // 1848
#define O_B   6216    // 1848
#define O_V2A 0       // aliases V1X (dead after P4')
#define O_V2B 2184    // aliases V1Y
#define S_FLOATS 8064 // 32,256 B

#define NBLK_X 16
#define NBLK_Y 16
#define NPLANES 24
#define NPARTIALS (NBLK_X*NBLK_Y*NPLANES)
#define TOTAL_ELEMS 6291456.0
#define INV121 (1.0f/121.0f)

__device__ __forceinline__ float4 ld4(const float* p) { return *(const float4*)p; }

__global__ __launch_bounds__(256) void sgf_loss_kernel(
    const float* __restrict__ gen, const float* __restrict__ ir,
    const float* __restrict__ vi, float* __restrict__ partials)
{
    __shared__ __align__(16) float S[S_FLOATS];
    const int tid = threadIdx.x;
    const int tx0 = blockIdx.x * TB;
    const int ty0 = blockIdx.y * TB;
    const size_t pbase = (size_t)blockIdx.z * (W * W);
    const bool colsafe = (tx0 != 0) && (tx0 != (W - TB));

    float acc = 0.0f;
    float F0 = 0.f, F1 = 0.f, F2 = 0.f, F3 = 0.f;   // flit state (named regs)

    #pragma unroll 1
    for (int img = 0; img < 3; ++img) {
        const float* __restrict__ X =
            (img == 0 ? ir : (img == 1 ? vi : gen)) + pbase;

        __syncthreads();   // V2 (aliases V1) read by prev P7' done before V1 writes

        // ---- P2': vertical 11-sums of x, x^2 from GLOBAL -> V1X, V1Y.
        // 182 tasks: cg 0..12 (V1 col-quad 4cg), ch 0..13 (V1 rows 3ch..3ch+2).
        // V1 row q <-> img row ty0-5+q; window img rows ty0-10+q .. ty0+q.
        if (tid < 182) {
            int ch = tid / 13, cg = tid - ch * 13;
            int c4 = cg * 4, q0 = ch * 3;
            int gxb = tx0 - 10 + c4;              // gxb % 4 == 2 -> float2 pairs
            float sx0=0,sx1=0,sx2=0,sx3=0, sy0=0,sy1=0,sy2=0,sy3=0;
            float r0, r1, r2, r3;
            float a00,a01,a02,a03, a10,a11,a12,a13;   // saved rows d=0,1

#define LOADR(GY)                                                             \
            {                                                                 \
                int gy_ = (GY);                                               \
                if ((unsigned)gy_ < (unsigned)W) {                            \
                    const float* Xr_ = X + (size_t)gy_ * W;                    \
                    if (colsafe) {                                            \
                        float2 p0_ = *(const float2*)(Xr_ + gxb);             \
                        float2 p1_ = *(const float2*)(Xr_ + gxb + 2);         \
                        r0 = p0_.x; r1 = p0_.y; r2 = p1_.x; r3 = p1_.y;       \
                    } else {                                                  \
                        r0 = ((unsigned)(gxb+0) < (unsigned)W) ? Xr_[gxb+0] : 0.f; \
                        r1 = ((unsigned)(gxb+1) < (unsigned)W) ? Xr_[gxb+1] : 0.f; \
                        r2 = ((unsigned)(gxb+2) < (unsigned)W) ? Xr_[gxb+2] : 0.f; \
                        r3 = ((unsigned)(gxb+3) < (unsigned)W) ? Xr_[gxb+3] : 0.f; \
                    }                                                         \
                } else { r0 = r1 = r2 = r3 = 0.f; }                           \
            }
#define ACCUM  { sx0+=r0; sx1+=r1; sx2+=r2; sx3+=r3;                          \
                 sy0=fmaf(r0,r0,sy0); sy1=fmaf(r1,r1,sy1);                    \
                 sy2=fmaf(r2,r2,sy2); sy3=fmaf(r3,r3,sy3); }

            LOADR(ty0 - 10 + q0 + 0); a00=r0;a01=r1;a02=r2;a03=r3; ACCUM
            LOADR(ty0 - 10 + q0 + 1); a10=r0;a11=r1;a12=r2;a13=r3; ACCUM
            #pragma unroll
            for (int d = 2; d < 10; ++d) { LOADR(ty0 - 10 + q0 + d) ACCUM }

            // out q0
            LOADR(ty0 + q0 + 0) ACCUM
            *(float4*)&S[O_V1X + (q0+0)*V1STR + c4] = make_float4(sx0,sx1,sx2,sx3);
            *(float4*)&S[O_V1Y + (q0+0)*V1STR + c4] = make_float4(sy0,sy1,sy2,sy3);
            // out q0+1: sub saved row 0, add next
            sx0-=a00; sx1-=a01; sx2-=a02; sx3-=a03;
            sy0=fmaf(-a00,a00,sy0); sy1=fmaf(-a01,a01,sy1);
            sy2=fmaf(-a02,a02,sy2); sy3=fmaf(-a03,a03,sy3);
            LOADR(ty0 + q0 + 1) ACCUM
            *(float4*)&S[O_V1X + (q0+1)*V1STR + c4] = make_float4(sx0,sx1,sx2,sx3);
            *(float4*)&S[O_V1Y + (q0+1)*V1STR + c4] = make_float4(sy0,sy1,sy2,sy3);
            // out q0+2: sub saved row 1, add next
            sx0-=a10; sx1-=a11; sx2-=a12; sx3-=a13;
            sy0=fmaf(-a10,a10,sy0); sy1=fmaf(-a11,a11,sy1);
            sy2=fmaf(-a12,a12,sy2); sy3=fmaf(-a13,a13,sy3);
            LOADR(ty0 + q0 + 2) ACCUM
            *(float4*)&S[O_V1X + (q0+2)*V1STR + c4] = make_float4(sx0,sx1,sx2,sx3);
            *(float4*)&S[O_V1Y + (q0+2)*V1STR + c4] = make_float4(sy0,sy1,sy2,sy3);
#undef LOADR
#undef ACCUM
        }
        __syncthreads();

        // ---- P4': horizontal 11-sums over V1 + pointwise a,b.
        // 462 tasks: r 0..41 (A row), cg 0..10 (A col-quad 4cg..4cg+3).
        // Window for out col c: V1 cols c..c+10.
        for (int t = tid; t < 462; t += 256) {
            int r = t / 11, cg = t - r * 11;
            int c4 = cg * 4;
            const float* vx = &S[O_V1X + r * V1STR + c4];
            const float* vy = &S[O_V1Y + r * V1STR + c4];
            float4 x0 = ld4(vx), x1 = ld4(vx+4), x2 = ld4(vx+8), x3 = ld4(vx+12);
            float4 y0 = ld4(vy), y1 = ld4(vy+4), y2 = ld4(vy+8), y3 = ld4(vy+12);
            float ox0 = x0.x+x0.y+x0.z+x0.w + x1.x+x1.y+x1.z+x1.w + x2.x+x2.y+x2.z;
            float ox1 = ox0 + x2.w - x0.x;
            float ox2 = ox1 + x3.x - x0.y;
            float ox3 = ox2 + x3.y - x0.z;
            float oy0 = y0.x+y0.y+y0.z+y0.w + y1.x+y1.y+y1.z+y1.w + y2.x+y2.y+y2.z;
            float oy1 = oy0 + y2.w - y0.x;
            float oy2 = oy1 + y3.x - y0.y;
            float oy3 = oy2 + y3.y - y0.z;
            float4 av, bv;
            int gy = ty0 - 5 + r;
            if ((unsigned)gy < (unsigned)W) {
                float mv0 = ((unsigned)(tx0-5+c4+0) < (unsigned)W) ? INV121 : 0.f;
                float mv1 = ((unsigned)(tx0-5+c4+1) < (unsigned)W) ? INV121 : 0.f;
                float mv2 = ((unsigned)(tx0-5+c4+2) < (unsigned)W) ? INV121 : 0.f;
                float mv3 = ((unsigned)(tx0-5+c4+3) < (unsigned)W) ? INV121 : 0.f;
                float m0=ox0*mv0, c0=oy0*mv0, m1=ox1*mv1, c1=oy1*mv1;
                float m2=ox2*mv2, c2=oy2*mv2, m3=ox3*mv3, c3=oy3*mv3;
                float va0=fmaf(-m0,m0,c0), va1=fmaf(-m1,m1,c1);
                float va2=fmaf(-m2,m2,c2), va3=fmaf(-m3,m3,c3);
                float a0=va0*__builtin_amdgcn_rcpf(va0+1e-6f);
                float a1=va1*__builtin_amdgcn_rcpf(va1+1e-6f);
                float a2=va2*__builtin_amdgcn_rcpf(va2+1e-6f);
                float a3=va3*__builtin_amdgcn_rcpf(va3+1e-6f);
                av = make_float4(a0,a1,a2,a3);
                bv = make_float4(fmaf(-a0,m0,m0), fmaf(-a1,m1,m1),
                                 fmaf(-a2,m2,m2), fmaf(-a3,m3,m3));
            } else { av = make_float4(0.f,0.f,0.f,0.f); bv = av; }
            *(float4*)&S[O_A + r * ABSTR + c4] = av;
            *(float4*)&S[O_B + r * ABSTR + c4] = bv;
        }
        __syncthreads();

        // ---- P6': vertical 11-sums over A,B -> V2A,V2B (alias V1, dead).
        // 88 tasks: cg 0..10, ch 0..7 (V2 rows 4ch..4ch+3). V2 row p <- A rows p..p+10.
        if (tid < 88) {
            int ch = tid / 11, cg = tid - ch * 11;
            int c4 = cg * 4, p0 = ch * 4;
            const float* Ap = &S[O_A + c4];
            const float* Bp = &S[O_B + c4];
            float sa0=0,sa1=0,sa2=0,sa3=0, sb0=0,sb1=0,sb2=0,sb3=0;
            #pragma unroll
            for (int d = 0; d < 10; ++d) {
                float4 a = ld4(Ap + (p0+d)*ABSTR);
                float4 b = ld4(Bp + (p0+d)*ABSTR);
                sa0+=a.x; sa1+=a.y; sa2+=a.z; sa3+=a.w;
                sb0+=b.x; sb1+=b.y; sb2+=b.z; sb3+=b.w;
            }
#define P6_ROW(J)                                                             \
            {                                                                 \
                int p = p0 + (J);                                             \
                float4 a = ld4(Ap + (p+10)*ABSTR);                            \
                float4 b = ld4(Bp + (p+10)*ABSTR);                            \
                sa0+=a.x; sa1+=a.y; sa2+=a.z; sa3+=a.w;                       \
                sb0+=b.x; sb1+=b.y; sb2+=b.z; sb3+=b.w;                       \
                *(float4*)&S[O_V2A + p*V2STR + c4] = make_float4(sa0,sa1,sa2,sa3); \
                *(float4*)&S[O_V2B + p*V2STR + c4] = make_float4(sb0,sb1,sb2,sb3); \
                float4 ao = ld4(Ap + p*ABSTR);                                \
                float4 bo = ld4(Bp + p*ABSTR);                                \
                sa0-=ao.x; sa1-=ao.y; sa2-=ao.z; sa3-=ao.w;                   \
                sb0-=bo.x; sb1-=bo.y; sb2-=bo.z; sb3-=bo.w;                   \
            }
            P6_ROW(0) P6_ROW(1) P6_ROW(2) P6_ROW(3)
#undef P6_ROW
        }
        __syncthreads();

        // ---- P7': horizontal 11-sums over V2 + finalize. 256 tasks:
        // r = tid>>3 (out row), cg = tid&7 (out cols 4cg..4cg+3).
        // Window for out col j: V2 cols j..j+10 (V2 col 0 = img tx0-5).
        {
            int r = tid >> 3, c4 = (tid & 7) * 4;
            const float* va = &S[O_V2A + r * V2STR + c4];
            const float* vb = &S[O_V2B + r * V2STR + c4];
            float4 a0 = ld4(va), a1 = ld4(va+4), a2 = ld4(va+8), a3 = ld4(va+12);
            float4 b0 = ld4(vb), b1 = ld4(vb+4), b2 = ld4(vb+8), b3 = ld4(vb+12);
            float oa0 = a0.x+a0.y+a0.z+a0.w + a1.x+a1.y+a1.z+a1.w + a2.x+a2.y+a2.z;
            float oa1 = oa0 + a2.w - a0.x;
            float oa2 = oa1 + a3.x - a0.y;
            float oa3 = oa2 + a3.y - a0.z;
            float ob0 = b0.x+b0.y+b0.z+b0.w + b1.x+b1.y+b1.z+b1.w + b2.x+b2.y+b2.z;
            float ob1 = ob0 + b2.w - b0.x;
            float ob2 = ob1 + b3.x - b0.y;
            float ob3 = ob2 + b3.y - b0.z;
            float4 xv = ld4(X + (size_t)(ty0 + r) * W + (tx0 + c4));
            float t0 = fmaf(oa0, xv.x, ob0), g0 = fmaf(-t0, INV121, xv.x);
            float t1 = fmaf(oa1, xv.y, ob1), g1 = fmaf(-t1, INV121, xv.y);
            float t2 = fmaf(oa2, xv.z, ob2), g2 = fmaf(-t2, INV121, xv.z);
            float t3 = fmaf(oa3, xv.w, ob3), g3 = fmaf(-t3, INV121, xv.w);
            if (img == 0) {
                F0 = fabsf(g0); F1 = fabsf(g1); F2 = fabsf(g2); F3 = fabsf(g3);
            } else if (img == 1) {
                F0 = fmaxf(F0, fabsf(g0)); F1 = fmaxf(F1, fabsf(g1));
                F2 = fmaxf(F2, fabsf(g2)); F3 = fmaxf(F3, fabsf(g3));
            } else {
                acc += fabsf(g0 - F0) + fabsf(g1 - F1)
                     + fabsf(g2 - F2) + fabsf(g3 - F3);
            }
        }
    } // img loop

    // block reduction: wave shuffle + cross-wave via LDS
    #pragma unroll
    for (int off = 32; off > 0; off >>= 1) acc += __shfl_down(acc, off);
    __syncthreads();                // all P7' LDS reads done before S reuse
    if ((tid & 63) == 0) S[tid >> 6] = acc;
    __syncthreads();
    if (tid == 0)
        partials[((blockIdx.z * NBLK_Y) + blockIdx.y) * NBLK_X + blockIdx.x] =
            S[0] + S[1] + S[2] + S[3];
}

__global__ __launch_bounds__(256) void sgf_final_reduce(
    const float* __restrict__ partials, float* __restrict__ out)
{
    __shared__ double sd[256];
    int tid = threadIdx.x;
    double s = 0.0;
    for (int i = tid; i < NPARTIALS; i += 256) s += (double)partials[i];
    sd[tid] = s;
    __syncthreads();
    for (int off = 128; off > 0; off >>= 1) {
        if (tid < off) sd[tid] += sd[tid + off];
        __syncthreads();
    }
    if (tid == 0) out[0] = (float)(sd[0] * (1.0 / TOTAL_ELEMS));
}

extern "C" void kernel_launch(void* const* d_in, const int* in_sizes, int n_in,
                              void* d_out, int out_size, void* d_ws, size_t ws_size,
                              hipStream_t stream) {
    const float* gen = (const float*)d_in[0];
    const float* ir  = (const float*)d_in[1];
    const float* vi  = (const float*)d_in[2];
    float* partials = (float*)d_ws;   // 6144 floats = 24 KB

    dim3 grid(NBLK_X, NBLK_Y, NPLANES);
    sgf_loss_kernel<<<grid, dim3(256), 0, stream>>>(gen, ir, vi, partials);
    sgf_final_reduce<<<1, dim3(256), 0, stream>>>(partials, (float*)d_out);
}

// Round 9
// 100.759 us; speedup vs baseline: 3.5396x; 1.6116x over previous
//
#include <hip/hip_runtime.h>
#include <hip/hip_bf16.h>

// Self-guided-filter loss, fused per 32x32 tile. v9 = v2 (best, 135us) with:
//  - P4: 154 tasks (3-row chains) instead of 77x6-row  [wider, shorter chains]
//  - P7: 256 tasks direct 11-tap, flit in 4 named regs [all waves, no F buffer]
//  - XCD-chunked block swizzle (6144 % 8 == 0, bijective)
// All LDS float4 strides % 4 == 0 (48 / 44 / 36). LDS 34.8KB -> 4 blocks/CU.
// (8,3,512,512) fp32, RADIUS=5 (k=11), EPS=1e-6.

#define W 512
#define TB 32
#define H1STR 48   // h1: 52 rows, cols 0..41 valid (42..47 junk, never used)
#define ABSTR 44   // A,B: 42 rows, cols 0..41 valid (42,43 junk, never used)
#define H2STR 36   // h2: 42 rows, cols 0..31

#define O_H1X 0        // 52*48 = 2496
#define O_H1Y 2496
#define O_A   4992     // 42*44 = 1848
#define O_B   6840
#define O_H2A 0        // aliases h1x (dead after P4)
#define O_H2B 2496     // aliases h1y
#define S_FLOATS 8688  // 34,752 B -> 4 blocks/CU

#define NBLK_X 16
#define NBLK_Y 16
#define NPLANES 24
#define NWG (NBLK_X*NBLK_Y*NPLANES)     // 6144, % 8 == 0
#define NPARTIALS NWG
#define TOTAL_ELEMS 6291456.0
#define INV121 (1.0f/121.0f)

__device__ __forceinline__ float4 ld4(const float* p) { return *(const float4*)p; }

__global__ __launch_bounds__(256, 4) void sgf_loss_kernel(
    const float* __restrict__ gen, const float* __restrict__ ir,
    const float* __restrict__ vi, float* __restrict__ partials)
{
    __shared__ __align__(16) float S[S_FLOATS];
    const int tid = threadIdx.x;

    // XCD-chunked bijective swizzle: consecutive swizzled ids stay on one XCD
    // and map to consecutive tiles (halo sharing in the XCD's private L2).
    const int bid = blockIdx.x;
    const int swz = (bid & 7) * (NWG / 8) + (bid >> 3);
    const int tx0 = (swz & (NBLK_X - 1)) * TB;
    const int ty0 = ((swz / NBLK_X) & (NBLK_Y - 1)) * TB;
    const size_t pbase = (size_t)(swz / (NBLK_X * NBLK_Y)) * (W * W);

    float acc = 0.0f;
    float F0 = 0.f, F1 = 0.f, F2 = 0.f, F3 = 0.f;   // flit state (named regs)

    #pragma unroll 1
    for (int img = 0; img < 3; ++img) {
        const float* __restrict__ X =
            (img == 0 ? ir : (img == 1 ? vi : gen)) + pbase;

        __syncthreads();   // h2 (aliased h1) reads in prev P7 done before P2 writes

        // ---- P2: global -> h1 horizontal 11-sums of x and x^2 (v2 verbatim).
        // 312 tasks: 52 rows x 6 col-groups of 8.
        for (int t = tid; t < 312; t += 256) {
            int r = t / 6, cg = t - r * 6;
            int j0 = cg * 8;
            float* hx = &S[O_H1X + r * H1STR + j0];
            float* hy = &S[O_H1Y + r * H1STR + j0];
            int gy = ty0 - 10 + r;
            if ((unsigned)gy >= (unsigned)W) {
                float4 z = make_float4(0.f, 0.f, 0.f, 0.f);
                *(float4*)hx = z; *(float4*)(hx + 4) = z;
                *(float4*)hy = z; *(float4*)(hy + 4) = z;
                continue;
            }
            const float* Xr = X + (size_t)gy * W;
            int gx0 = tx0 - 12 + j0;           // 16B-aligned
            float w[20];
            if (gx0 >= 0 && gx0 + 20 <= W) {
                const float4* p = (const float4*)(Xr + gx0);
                float4 v0 = p[0], v1 = p[1], v2 = p[2], v3 = p[3], v4 = p[4];
                w[0]=v0.x;  w[1]=v0.y;  w[2]=v0.z;  w[3]=v0.w;
                w[4]=v1.x;  w[5]=v1.y;  w[6]=v1.z;  w[7]=v1.w;
                w[8]=v2.x;  w[9]=v2.y;  w[10]=v2.z; w[11]=v2.w;
                w[12]=v3.x; w[13]=v3.y; w[14]=v3.z; w[15]=v3.w;
                w[16]=v4.x; w[17]=v4.y; w[18]=v4.z; w[19]=v4.w;
            } else {
                #pragma unroll
                for (int k = 0; k < 20; ++k) {
                    int gx = gx0 + k;
                    w[k] = ((unsigned)gx < (unsigned)W) ? Xr[gx] : 0.f;
                }
            }
            float o[8], u[8];
            float s = w[2]+w[3]+w[4]+w[5]+w[6]+w[7]+w[8]+w[9]+w[10]+w[11]+w[12];
            o[0] = s;
            #pragma unroll
            for (int k = 1; k < 8; ++k) { s += w[12+k] - w[1+k]; o[k] = s; }
            float sq[20];
            #pragma unroll
            for (int k = 2; k < 20; ++k) sq[k] = w[k] * w[k];
            float s2 = sq[2]+sq[3]+sq[4]+sq[5]+sq[6]+sq[7]+sq[8]+sq[9]+sq[10]+sq[11]+sq[12];
            u[0] = s2;
            #pragma unroll
            for (int k = 1; k < 8; ++k) { s2 += sq[12+k] - sq[1+k]; u[k] = s2; }
            *(float4*)hx       = make_float4(o[0], o[1], o[2], o[3]);
            *(float4*)(hx + 4) = make_float4(o[4], o[5], o[6], o[7]);
            *(float4*)hy       = make_float4(u[0], u[1], u[2], u[3]);
            *(float4*)(hy + 4) = make_float4(u[4], u[5], u[6], u[7]);
        }
        __syncthreads();

        // ---- P4: vertical 11-sums over h1 -> a,b. 154 tasks, 3-row chains:
        // chunk 0..13 (A rows 3c..3c+2), cg 0..10 (cols 4cg..4cg+3).
        if (tid < 154) {
            int chunk = tid / 11, cg = tid - chunk * 11;
            int q0 = chunk * 3, c4 = cg * 4;
            float mv0 = ((unsigned)(tx0-5+c4+0) < (unsigned)W) ? INV121 : 0.f;
            float mv1 = ((unsigned)(tx0-5+c4+1) < (unsigned)W) ? INV121 : 0.f;
            float mv2 = ((unsigned)(tx0-5+c4+2) < (unsigned)W) ? INV121 : 0.f;
            float mv3 = ((unsigned)(tx0-5+c4+3) < (unsigned)W) ? INV121 : 0.f;
            const float* hx = &S[O_H1X + c4];
            const float* hy = &S[O_H1Y + c4];
            float sx0=0,sx1=0,sx2=0,sx3=0, sy0=0,sy1=0,sy2=0,sy3=0;
            #pragma unroll
            for (int d = 0; d < 10; ++d) {
                float4 xn = ld4(hx + (q0+d)*H1STR);
                float4 yn = ld4(hy + (q0+d)*H1STR);
                sx0+=xn.x; sx1+=xn.y; sx2+=xn.z; sx3+=xn.w;
                sy0+=yn.x; sy1+=yn.y; sy2+=yn.z; sy3+=yn.w;
            }
#define P4_ROW(J)                                                             \
            {                                                                 \
                int q = q0 + (J);                                             \
                float4 xn = ld4(hx + (q+10)*H1STR);                           \
                float4 yn = ld4(hy + (q+10)*H1STR);                           \
                sx0+=xn.x; sx1+=xn.y; sx2+=xn.z; sx3+=xn.w;                   \
                sy0+=yn.x; sy1+=yn.y; sy2+=yn.z; sy3+=yn.w;                   \
                int gy = ty0 - 5 + q;                                         \
                float4 av, bv;                                                \
                if ((unsigned)gy < (unsigned)W) {                             \
                    float m0=sx0*mv0, c0=sy0*mv0, m1=sx1*mv1, c1=sy1*mv1;     \
                    float m2=sx2*mv2, c2=sy2*mv2, m3=sx3*mv3, c3=sy3*mv3;     \
                    float va0=fmaf(-m0,m0,c0), va1=fmaf(-m1,m1,c1);           \
                    float va2=fmaf(-m2,m2,c2), va3=fmaf(-m3,m3,c3);           \
                    float a0=va0*__builtin_amdgcn_rcpf(va0+1e-6f);            \
                    float a1=va1*__builtin_amdgcn_rcpf(va1+1e-6f);            \
                    float a2=va2*__builtin_amdgcn_rcpf(va2+1e-6f);            \
                    float a3=va3*__builtin_amdgcn_rcpf(va3+1e-6f);            \
                    av = make_float4(a0,a1,a2,a3);                            \
                    bv = make_float4(fmaf(-a0,m0,m0), fmaf(-a1,m1,m1),        \
                                     fmaf(-a2,m2,m2), fmaf(-a3,m3,m3));       \
                } else { av = make_float4(0.f,0.f,0.f,0.f); bv = av; }        \
                *(float4*)&S[O_A + q*ABSTR + c4] = av;                        \
                *(float4*)&S[O_B + q*ABSTR + c4] = bv;                        \
                float4 xo = ld4(hx + q*H1STR);                                \
                float4 yo = ld4(hy + q*H1STR);                                \
                sx0-=xo.x; sx1-=xo.y; sx2-=xo.z; sx3-=xo.w;                   \
                sy0-=yo.x; sy1-=yo.y; sy2-=yo.z; sy3-=yo.w;                   \
            }
            P4_ROW(0) P4_ROW(1) P4_ROW(2)
#undef P4_ROW
        }
        __syncthreads();

        // ---- P6: horizontal 11-sums of a,b -> h2a,h2b (v2 verbatim).
        // 168 tasks (r 0..41, cg 0..3 -> 8 output cols each).
        if (tid < 168) {
            int r = tid >> 2, cg = tid & 3;
            int j0 = cg * 8;
            const float* Ap = &S[O_A + r * ABSTR + j0];
            const float* Bp = &S[O_B + r * ABSTR + j0];
            float wa[20], wb[20];
            #pragma unroll
            for (int k = 0; k < 5; ++k) {
                float4 va = ld4(Ap + 4 * k);
                wa[4*k]=va.x; wa[4*k+1]=va.y; wa[4*k+2]=va.z; wa[4*k+3]=va.w;
                float4 vb = ld4(Bp + 4 * k);
                wb[4*k]=vb.x; wb[4*k+1]=vb.y; wb[4*k+2]=vb.z; wb[4*k+3]=vb.w;
            }
            float oa[8], ob[8];
            float s = wa[0]+wa[1]+wa[2]+wa[3]+wa[4]+wa[5]+wa[6]+wa[7]+wa[8]+wa[9]+wa[10];
            oa[0] = s;
            #pragma unroll
            for (int k = 1; k < 8; ++k) { s += wa[10+k] - wa[k-1]; oa[k] = s; }
            float s2 = wb[0]+wb[1]+wb[2]+wb[3]+wb[4]+wb[5]+wb[6]+wb[7]+wb[8]+wb[9]+wb[10];
            ob[0] = s2;
            #pragma unroll
            for (int k = 1; k < 8; ++k) { s2 += wb[10+k] - wb[k-1]; ob[k] = s2; }
            float* da = &S[O_H2A + r * H2STR + j0];
            float* db = &S[O_H2B + r * H2STR + j0];
            *(float4*)da       = make_float4(oa[0], oa[1], oa[2], oa[3]);
            *(float4*)(da + 4) = make_float4(oa[4], oa[5], oa[6], oa[7]);
            *(float4*)db       = make_float4(ob[0], ob[1], ob[2], ob[3]);
            *(float4*)(db + 4) = make_float4(ob[4], ob[5], ob[6], ob[7]);
        }
        __syncthreads();

        // ---- P7: DIRECT 11-tap vertical over h2 -> f; 256 tasks (all waves).
        // r = tid>>3 (out row 0..31), cg = tid&7 (cols 4cg..4cg+3).
        {
            int r = tid >> 3, c4 = (tid & 7) * 4;
            const float* ha = &S[O_H2A + c4];
            const float* hb = &S[O_H2B + c4];
            float sa0=0,sa1=0,sa2=0,sa3=0, sb0=0,sb1=0,sb2=0,sb3=0;
            #pragma unroll
            for (int d = 0; d < 11; ++d) {
                float4 a = ld4(ha + (r+d)*H2STR);
                float4 b = ld4(hb + (r+d)*H2STR);
                sa0+=a.x; sa1+=a.y; sa2+=a.z; sa3+=a.w;
                sb0+=b.x; sb1+=b.y; sb2+=b.z; sb3+=b.w;
            }
            float4 xv = ld4(X + (size_t)(ty0 + r) * W + (tx0 + c4));
            float t0 = fmaf(sa0, xv.x, sb0), g0 = fmaf(-t0, INV121, xv.x);
            float t1 = fmaf(sa1, xv.y, sb1), g1 = fmaf(-t1, INV121, xv.y);
            float t2 = fmaf(sa2, xv.z, sb2), g2 = fmaf(-t2, INV121, xv.z);
            float t3 = fmaf(sa3, xv.w, sb3), g3 = fmaf(-t3, INV121, xv.w);
            if (img == 0) {
                F0 = fabsf(g0); F1 = fabsf(g1); F2 = fabsf(g2); F3 = fabsf(g3);
            } else if (img == 1) {
                F0 = fmaxf(F0, fabsf(g0)); F1 = fmaxf(F1, fabsf(g1));
                F2 = fmaxf(F2, fabsf(g2)); F3 = fmaxf(F3, fabsf(g3));
            } else {
                acc += fabsf(g0 - F0) + fabsf(g1 - F1)
                     + fabsf(g2 - F2) + fabsf(g3 - F3);
            }
        }
    } // img loop

    // block reduction: wave shuffle + cross-wave via LDS
    #pragma unroll
    for (int off = 32; off > 0; off >>= 1) acc += __shfl_down(acc, off);
    __syncthreads();                // all P7 LDS reads done before S reuse
    if ((tid & 63) == 0) S[tid >> 6] = acc;
    __syncthreads();
    if (tid == 0)
        partials[swz] = S[0] + S[1] + S[2] + S[3];
}

__global__ __launch_bounds__(256) void sgf_final_reduce(
    const float* __restrict__ partials, float* __restrict__ out)
{
    __shared__ double sd[256];
    int tid = threadIdx.x;
    double s = 0.0;
    for (int i = tid; i < NPARTIALS; i += 256) s += (double)partials[i];
    sd[tid] = s;
    __syncthreads();
    for (int off = 128; off > 0; off >>= 1) {
        if (tid < off) sd[tid] += sd[tid + off];
        __syncthreads();
    }
    if (tid == 0) out[0] = (float)(sd[0] * (1.0 / TOTAL_ELEMS));
}

extern "C" void kernel_launch(void* const* d_in, const int* in_sizes, int n_in,
                              void* d_out, int out_size, void* d_ws, size_t ws_size,
                              hipStream_t stream) {
    const float* gen = (const float*)d_in[0];
    const float* ir  = (const float*)d_in[1];
    const float* vi  = (const float*)d_in[2];
    float* partials = (float*)d_ws;   // 6144 floats = 24 KB

    sgf_loss_kernel<<<dim3(NWG), dim3(256), 0, stream>>>(gen, ir, vi, partials);
    sgf_final_reduce<<<1, dim3(256), 0, stream>>>(partials, (float*)d_out);
}